// Round 19
// baseline (131.378 us; speedup 1.0000x reference)
//
#include <hip/hip_runtime.h>
#include <hip/hip_bf16.h>

// GPT2 attention. B=2, S=2048, D=1024, H=16, DH=64.
// inputs (f32): x[2,2048,1024], w_attn[1024,3072], b_attn[3072], w_proj[1024,1024], b_proj[1024]
// output (f32): [2,2048,1024]

#define BB 2
#define SS 2048
#define DD 1024
#define HH 16
#define DHH 64
#define MTOK (BB * SS)        // 4096
#define N3D (3 * DD)          // 3072
// 1/sqrt(64) * log2(e): softmax runs in exp2 domain
#define QSCALE 0.18033688f

typedef __attribute__((ext_vector_type(8))) short bf16x8;
typedef __attribute__((ext_vector_type(4))) float f32x4;
typedef __attribute__((ext_vector_type(4))) short short4v;

__device__ __forceinline__ short f2bf(float f) {
  unsigned int x = __float_as_uint(f);
  unsigned int r = (x + 0x7fffu + ((x >> 16) & 1u)) >> 16;
  return (short)r;
}

__device__ __forceinline__ unsigned int cvtpk_bf16(float lo, float hi) {
  unsigned int r;
  asm("v_cvt_pk_bf16_f32 %0, %1, %2" : "=v"(r) : "v"(lo), "v"(hi));
  return r;
}

// native 2^x (v_exp_f32 IS exp2); plain exp2f() lowers to an ocml libcall.
__device__ __forceinline__ float exp2n(float x) {
  float r;
  asm("v_exp_f32 %0, %1" : "=v"(r) : "v"(x));
  return r;
}

// ---------------- prep: w_attn transpose + w_proj transpose (x-cast fused into QKV GEMM) ----------------
__global__ __launch_bounds__(256) void prep_k(const float* __restrict__ wa, short* __restrict__ waT,
                                              const float* __restrict__ wp, short* __restrict__ wpT) {
  __shared__ float t[32][33];
  int bid = blockIdx.x, tid = threadIdx.x;
  const float* W; short* Wt; int K, N, n0, k0;
  if (bid < 3072) {
    W = wa; Wt = waT; K = 1024; N = 3072;
    n0 = (bid % 96) * 32; k0 = (bid / 96) * 32;
  } else {
    int id = bid - 3072;
    W = wp; Wt = wpT; K = 1024; N = 1024;
    n0 = (id & 31) * 32; k0 = (id >> 5) * 32;
  }
  int tx = tid & 31, ty = tid >> 5;
#pragma unroll
  for (int i = 0; i < 4; ++i)
    t[ty + 8 * i][tx] = W[(size_t)(k0 + ty + 8 * i) * N + n0 + tx];
  __syncthreads();
#pragma unroll
  for (int i = 0; i < 4; ++i)
    Wt[(size_t)(n0 + ty + 8 * i) * K + k0 + tx] = f2bf(t[tx][ty + 8 * i]);
}

// ---------------- QKV GEMM: f32 A staged via global_load_lds, in-register cvt to bf16 ----------------
// qkv[4096][3072] = x[4096][1024] @ wattnT[3072][1024]^T + bias. Q cols pre-scaled by
// QSCALE; V cols written transposed to vtout. A-tile f32 (32KB, blk^(row&15) swizzle,
// 2-way read aliasing = free); B-tile bf16 as before. Fragments: 2x ds_read_b128 f32 +
// 4x v_cvt_pk_bf16_f32 (RNE == old prep cast, bitwise identical). LDS 48KB.
__global__ __launch_bounds__(256) void gemm128_qkv_k(const float* __restrict__ X,
                                                     const short* __restrict__ Bt,
                                                     const float* __restrict__ bias,
                                                     short* __restrict__ qkv,
                                                     short* __restrict__ vtout) {
  __shared__ float Asf[128 * 64];
  __shared__ short Bs[128 * 64];
  constexpr int NX = 24, CHUNK = 96;  // 768 blocks, XCD-chunked
  int tid = threadIdx.x;
  int swz = (blockIdx.x & 7) * CHUNK + (blockIdx.x >> 3);
  int m0 = (swz / NX) * 128, n0 = (swz % NX) * 128;
  int w = tid >> 6, lane = tid & 63;
  int wr = w >> 1, wc = w & 1;
  int ln16 = lane & 15, l16 = lane >> 4;

  f32x4 acc[4][4] = {};

  // B staging (bf16): 8 16B-blocks/row, blk^(row&7)
  int lrow0 = w * 32 + (lane >> 3);
  int blk_p = lane & 7;
  // A staging (f32): chunk c = w*8+i covers rows [4c,4c+4); lane -> row 4c+(lane>>4),
  // 16B-block lane&15 of 16/row; source col pre-swizzled blk^(row&15)
  int arow_in = lane >> 4;
  int ablk = lane & 15;

#pragma unroll 1
  for (int k0 = 0; k0 < 1024; k0 += 64) {
#pragma unroll
    for (int i = 0; i < 8; ++i) {
      int c = w * 8 + i;
      int row = c * 4 + arow_in;
      int colE = ((ablk ^ (row & 15)) << 2);  // f32 elems
      __builtin_amdgcn_global_load_lds(
          (const __attribute__((address_space(1))) unsigned int*)&X[(size_t)(m0 + row) * 1024 + k0 + colE],
          (__attribute__((address_space(3))) unsigned int*)&Asf[c * 256],
          16, 0, 0);
    }
#pragma unroll
    for (int i = 0; i < 4; ++i) {
      int row_p = lrow0 + i * 8;
      int colE = ((blk_p ^ (row_p & 7)) << 3);
      __builtin_amdgcn_global_load_lds(
          (const __attribute__((address_space(1))) unsigned int*)&Bt[(size_t)(n0 + row_p) * 1024 + k0 + colE],
          (__attribute__((address_space(3))) unsigned int*)&Bs[(w * 4 + i) * 512],
          16, 0, 0);
    }
    __syncthreads();
#pragma unroll
    for (int kk = 0; kk < 2; ++kk) {
      bf16x8 a[4], bfr[4];
#pragma unroll
      for (int mi = 0; mi < 4; ++mi) {
        int row = wr * 64 + mi * 16 + ln16;
        int b0 = (kk * 8 + l16 * 2) ^ (row & 15);
        int b1 = (kk * 8 + l16 * 2 + 1) ^ (row & 15);
        float4 lo = *reinterpret_cast<const float4*>(&Asf[row * 64 + b0 * 4]);
        float4 hi = *reinterpret_cast<const float4*>(&Asf[row * 64 + b1 * 4]);
        uint4 uu;
        uu.x = cvtpk_bf16(lo.x, lo.y);
        uu.y = cvtpk_bf16(lo.z, lo.w);
        uu.z = cvtpk_bf16(hi.x, hi.y);
        uu.w = cvtpk_bf16(hi.z, hi.w);
        a[mi] = *reinterpret_cast<bf16x8*>(&uu);
      }
#pragma unroll
      for (int ni = 0; ni < 4; ++ni) {
        int row = wc * 64 + ni * 16 + ln16;
        int blk = (kk * 4 + l16) ^ (row & 7);
        bfr[ni] = *reinterpret_cast<const bf16x8*>(&Bs[row * 64 + blk * 8]);
      }
#pragma unroll
      for (int mi = 0; mi < 4; ++mi)
#pragma unroll
        for (int ni = 0; ni < 4; ++ni)
          acc[mi][ni] = __builtin_amdgcn_mfma_f32_16x16x32_bf16(a[mi], bfr[ni], acc[mi][ni], 0, 0, 0);
    }
    __syncthreads();
  }

#pragma unroll
  for (int mi = 0; mi < 4; ++mi)
#pragma unroll
    for (int ni = 0; ni < 4; ++ni)
#pragma unroll
      for (int ri = 0; ri < 4; ++ri) {
        int row = m0 + wr * 64 + mi * 16 + l16 * 4 + ri;
        int col = n0 + wc * 64 + ni * 16 + ln16;
        float v = acc[mi][ni][ri] + bias[col];
        if (n0 < DD) v *= QSCALE;  // Q block (uniform per block)
        short bv = f2bf(v);
        if (n0 >= 2 * DD) {
          int bb = row >> 11, s = row & 2047;
          vtout[(size_t)(bb * 1024 + col - 2 * DD) * SS + s] = bv;
        } else {
          qkv[(size_t)row * N3D + col] = bv;
        }
      }
}

// ---------------- proj GEMM (m97 structure, compile-time dims, XCD-chunked) ----------------
template <int M, int N, int K>
__global__ __launch_bounds__(256) void gemm128_proj_k(const short* __restrict__ A,
                                                      const short* __restrict__ Bt,
                                                      const float* __restrict__ bias,
                                                      float* __restrict__ Cout) {
  __shared__ short As[128 * 64];
  __shared__ short Bs[128 * 64];
  constexpr int NX = N / 128;
  constexpr int NWG = NX * (M / 128);
  constexpr int CHUNK = NWG / 8;
  int tid = threadIdx.x;
  int swz = (blockIdx.x & 7) * CHUNK + (blockIdx.x >> 3);
  int m0 = (swz / NX) * 128, n0 = (swz % NX) * 128;
  int w = tid >> 6, lane = tid & 63;
  int wr = w >> 1, wc = w & 1;
  int ln16 = lane & 15, l16 = lane >> 4;

  f32x4 acc[4][4] = {};

  int lrow0 = w * 32 + (lane >> 3);
  int blk_p = lane & 7;

#pragma unroll 1
  for (int k0 = 0; k0 < K; k0 += 64) {
#pragma unroll
    for (int i = 0; i < 4; ++i) {
      int row_p = lrow0 + i * 8;
      int colE = ((blk_p ^ (row_p & 7)) << 3);
      __builtin_amdgcn_global_load_lds(
          (const __attribute__((address_space(1))) unsigned int*)&A[(size_t)(m0 + row_p) * K + k0 + colE],
          (__attribute__((address_space(3))) unsigned int*)&As[(w * 4 + i) * 512],
          16, 0, 0);
      __builtin_amdgcn_global_load_lds(
          (const __attribute__((address_space(1))) unsigned int*)&Bt[(size_t)(n0 + row_p) * K + k0 + colE],
          (__attribute__((address_space(3))) unsigned int*)&Bs[(w * 4 + i) * 512],
          16, 0, 0);
    }
    __syncthreads();
#pragma unroll
    for (int kk = 0; kk < 2; ++kk) {
      bf16x8 a[4], bfr[4];
#pragma unroll
      for (int mi = 0; mi < 4; ++mi) {
        int row = wr * 64 + mi * 16 + ln16;
        int blk = (kk * 4 + l16) ^ (row & 7);
        a[mi] = *reinterpret_cast<const bf16x8*>(&As[row * 64 + blk * 8]);
      }
#pragma unroll
      for (int ni = 0; ni < 4; ++ni) {
        int row = wc * 64 + ni * 16 + ln16;
        int blk = (kk * 4 + l16) ^ (row & 7);
        bfr[ni] = *reinterpret_cast<const bf16x8*>(&Bs[row * 64 + blk * 8]);
      }
#pragma unroll
      for (int mi = 0; mi < 4; ++mi)
#pragma unroll
        for (int ni = 0; ni < 4; ++ni)
          acc[mi][ni] = __builtin_amdgcn_mfma_f32_16x16x32_bf16(a[mi], bfr[ni], acc[mi][ni], 0, 0, 0);
    }
    __syncthreads();
  }

#pragma unroll
  for (int mi = 0; mi < 4; ++mi)
#pragma unroll
    for (int ni = 0; ni < 4; ++ni)
#pragma unroll
      for (int ri = 0; ri < 4; ++ri) {
        int row = m0 + wr * 64 + mi * 16 + l16 * 4 + ri;
        int col = n0 + wc * 64 + ni * 16 + ln16;
        Cout[(size_t)row * N + col] = acc[mi][ni][ri] + bias[col];
      }
}

// ---------------- Flash attention (R17 form: l-via-ones-MFMA, setprio, XCD swizzle) ----------------
#define MASKV -3.0e38f
__global__ __launch_bounds__(512) void flash_attn_k(const short* __restrict__ qkv,
                                                    const short* __restrict__ vt,
                                                    short* __restrict__ ctx) {
  __shared__ __align__(16) char smem[53248];
  // [0,18432): Ks[2][64][72] ; [18432,36864): Vs[2][64][72] ; [36864,53248): Ps 8*16*64 shorts
  // (XOR-swizzled 16B blocks). Combine aliases: Od f32 dump at [0,16640), mls at [17408,17920),
  // lls (l dump, cacc-row layout) at [17920,18432).
  short (*Ks)[64][72] = reinterpret_cast<short(*)[64][72]>(smem);
  short (*Vs)[64][72] = reinterpret_cast<short(*)[64][72]>(smem + 18432);
  short* Psr = reinterpret_cast<short*>(smem + 36864);
  float* Od = reinterpret_cast<float*>(smem);
  float* mls = reinterpret_cast<float*>(smem + 17408);
  float* lls = reinterpret_cast<float*>(smem + 17920);

  int tid = threadIdx.x;
  // XCD-chunked swizzle: same-head blocks share an XCD L2.
  int orig = blockIdx.x;                    // 0..511
  int wg = (orig & 7) * 64 + (orig >> 3);   // bijective (512 % 8 == 0)
  int bh = wg >> 4;
  int pj = wg & 15;
  int b = bh >> 4, h = bh & 15;
  int wgv = tid >> 6, lane = tid & 63;
  int g = wgv >> 2, wq = wgv & 3;
  int ln16 = lane & 15, l16 = lane >> 4;
  int t8 = tid & 255;
  int tb = tid >> 8;  // staging parity buffer this thread fills
  int r0 = t8 >> 3, cc0 = (t8 & 7) << 3;
  int psq = (wgv << 10) + (ln16 << 6);  // Ps base (shorts) for this wave+q

  // all-ones bf16x8 (1.0 = 0x3F80) for the l row-sum MFMA
  bf16x8 vone;
#pragma unroll
  for (int j = 0; j < 8; ++j) vone[j] = (short)0x3F80;

  const short* kbase = qkv + (size_t)(b * SS) * N3D + DD + h * DHH;  // + s*N3D + d
  const short* vbase = vt + (size_t)(bh * DHH) * SS;                 // + d*SS + s

#pragma unroll 1
  for (int ti = 0; ti < 2; ++ti) {
    int qt = ti ? pj : 31 - pj;
    int q0 = qt * 64;

    bf16x8 qf[2];
    {
      const short* qrow = qkv + (size_t)(b * SS + q0 + wq * 16 + ln16) * N3D + h * DHH;
      qf[0] = *reinterpret_cast<const bf16x8*>(qrow + l16 * 8);
      qf[1] = *reinterpret_cast<const bf16x8*>(qrow + 32 + l16 * 8);
    }
    float m_ = -1e30f;
    f32x4 cacc[4] = {};
    f32x4 lacc = {};

    int ns = (qt + 2) >> 1;
    uint4 kr0, kr1, vr0, vr1;
    {
      int kt_s = tb <= qt ? tb : qt;
      kr0 = *reinterpret_cast<const uint4*>(kbase + (size_t)(kt_s * 64 + r0) * N3D + cc0);
      kr1 = *reinterpret_cast<const uint4*>(kbase + (size_t)(kt_s * 64 + r0 + 32) * N3D + cc0);
      vr0 = *reinterpret_cast<const uint4*>(vbase + (size_t)r0 * SS + kt_s * 64 + cc0);
      vr1 = *reinterpret_cast<const uint4*>(vbase + (size_t)(r0 + 32) * SS + kt_s * 64 + cc0);
    }

#pragma unroll 1
    for (int s = 0; s < ns; ++s) {
      *reinterpret_cast<uint4*>(&Ks[tb][r0][cc0]) = kr0;
      *reinterpret_cast<uint4*>(&Ks[tb][r0 + 32][cc0]) = kr1;
      *reinterpret_cast<uint4*>(&Vs[tb][r0][cc0]) = vr0;
      *reinterpret_cast<uint4*>(&Vs[tb][r0 + 32][cc0]) = vr1;
      __syncthreads();

      // prefetch next super-iter (clamped; latency hides under softmax+PV)
      {
        int kt_n = 2 * (s + 1) + tb;
        if (kt_n > qt) kt_n = qt;
        kr0 = *reinterpret_cast<const uint4*>(kbase + (size_t)(kt_n * 64 + r0) * N3D + cc0);
        kr1 = *reinterpret_cast<const uint4*>(kbase + (size_t)(kt_n * 64 + r0 + 32) * N3D + cc0);
        vr0 = *reinterpret_cast<const uint4*>(vbase + (size_t)r0 * SS + kt_n * 64 + cc0);
        vr1 = *reinterpret_cast<const uint4*>(vbase + (size_t)(r0 + 32) * SS + kt_n * 64 + cc0);
      }

      int kt_c = 2 * s + g;
      if (kt_c <= qt) {
        // QK^T swapped: sacc[ni][ri] = S^T[k = ni*16+l16*4+ri][q = ln16]  (log2-scaled)
        f32x4 sacc[4] = {};
        __builtin_amdgcn_s_setprio(1);
#pragma unroll
        for (int kk = 0; kk < 2; ++kk)
#pragma unroll
          for (int ni = 0; ni < 4; ++ni) {
            bf16x8 kf = *reinterpret_cast<const bf16x8*>(&Ks[g][ni * 16 + ln16][kk * 32 + l16 * 8]);
            sacc[ni] = __builtin_amdgcn_mfma_f32_16x16x32_bf16(kf, qf[kk], sacc[ni], 0, 0, 0);
          }
        __builtin_amdgcn_s_setprio(0);

        float p[4][4];
        float mx = MASKV;
        if (kt_c == qt) {  // diagonal tile: causal mask
          int qg = q0 + wq * 16 + ln16;
#pragma unroll
          for (int ni = 0; ni < 4; ++ni)
#pragma unroll
            for (int ri = 0; ri < 4; ++ri) {
              int kg = kt_c * 64 + ni * 16 + l16 * 4 + ri;
              float v = (kg > qg) ? MASKV : sacc[ni][ri];
              p[ni][ri] = v;
              mx = fmaxf(mx, v);
            }
        } else {
#pragma unroll
          for (int ni = 0; ni < 4; ++ni)
#pragma unroll
            for (int ri = 0; ri < 4; ++ri) {
              p[ni][ri] = sacc[ni][ri];
              mx = fmaxf(mx, sacc[ni][ri]);
            }
        }
        mx = fmaxf(mx, __shfl_xor(mx, 16));
        mx = fmaxf(mx, __shfl_xor(mx, 32));

        // defer-max (T13), log2 domain: rescale only when max grew by > 11.5
        int keep = __all(mx <= m_ + 11.5f);
        float mn = m_;
        if (!keep) {
          mn = fmaxf(m_, mx);
          float sc = exp2n(m_ - mn);
          float scr[4];
#pragma unroll
          for (int ri = 0; ri < 4; ++ri) scr[ri] = __shfl(sc, l16 * 4 + ri);
#pragma unroll
          for (int di = 0; di < 4; ++di)
#pragma unroll
            for (int ri = 0; ri < 4; ++ri) cacc[di][ri] *= scr[ri];
#pragma unroll
          for (int ri = 0; ri < 4; ++ri) lacc[ri] *= scr[ri];
          m_ = mn;
        }

#pragma unroll
        for (int ni = 0; ni < 4; ++ni)
#pragma unroll
          for (int ri = 0; ri < 4; ++ri)
            p[ni][ri] = exp2n(p[ni][ri] - mn);

        // pack P -> Ps[wave][q=ln16][k], XOR-swizzled 16B blocks (blk ^= q&7)
#pragma unroll
        for (int ni = 0; ni < 4; ++ni) {
          uint2 u;
          u.x = cvtpk_bf16(p[ni][0], p[ni][1]);
          u.y = cvtpk_bf16(p[ni][2], p[ni][3]);
          int idx = psq + ((((ni << 1) + (l16 >> 1)) ^ (ln16 & 7)) << 3) + ((l16 & 1) << 2);
          *reinterpret_cast<uint2*>(&Psr[idx]) = u;
        }
        asm volatile("s_waitcnt lgkmcnt(0)" ::: "memory");

        // ctx += P @ V ; l += P @ ones (same C-layout: row = l16*4+ri)
        __builtin_amdgcn_s_setprio(1);
#pragma unroll
        for (int kk = 0; kk < 2; ++kk) {
          bf16x8 pa = *reinterpret_cast<const bf16x8*>(
              &Psr[psq + ((((kk << 2) + l16) ^ (ln16 & 7)) << 3)]);
          lacc = __builtin_amdgcn_mfma_f32_16x16x32_bf16(pa, vone, lacc, 0, 0, 0);
#pragma unroll
          for (int di = 0; di < 4; ++di) {
            bf16x8 vb = *reinterpret_cast<const bf16x8*>(&Vs[g][di * 16 + ln16][kk * 32 + l16 * 8]);
            cacc[di] = __builtin_amdgcn_mfma_f32_16x16x32_bf16(pa, vb, cacc[di], 0, 0, 0);
          }
        }
        __builtin_amdgcn_s_setprio(0);
      }
      __syncthreads();
    }

    // ---- combine even/odd partials (aliases Ks/Vs region; all kv reads done) ----
    if (g == 1) {
      if (l16 == 0) mls[wq * 16 + ln16] = m_;
      if (ln16 == 0)
#pragma unroll
        for (int ri = 0; ri < 4; ++ri) lls[wq * 16 + l16 * 4 + ri] = lacc[ri];
#pragma unroll
      for (int di = 0; di < 4; ++di)
#pragma unroll
        for (int ri = 0; ri < 4; ++ri)
          Od[wq * 1040 + (l16 * 4 + ri) * 65 + di * 16 + ln16] = cacc[di][ri];
    }
    __syncthreads();
    if (g == 0) {
      float m1 = mls[wq * 16 + ln16];
      float mM = fmaxf(m_, m1);
      float e0 = exp2n(m_ - mM), e1 = exp2n(m1 - mM);
      float e0r[4], e1r[4], ivr[4];
#pragma unroll
      for (int ri = 0; ri < 4; ++ri) {
        int src = l16 * 4 + ri;
        e0r[ri] = __shfl(e0, src);
        e1r[ri] = __shfl(e1, src);
      }
#pragma unroll
      for (int ri = 0; ri < 4; ++ri) {
        float l1 = lls[wq * 16 + l16 * 4 + ri];
        ivr[ri] = 1.f / (lacc[ri] * e0r[ri] + l1 * e1r[ri]);
      }
#pragma unroll
      for (int di = 0; di < 4; ++di)
#pragma unroll
        for (int ri = 0; ri < 4; ++ri) {
          float a1 = Od[wq * 1040 + (l16 * 4 + ri) * 65 + di * 16 + ln16];
          float o = (cacc[di][ri] * e0r[ri] + a1 * e1r[ri]) * ivr[ri];
          int row = q0 + wq * 16 + l16 * 4 + ri;
          int col = h * DHH + di * 16 + ln16;
          ctx[(size_t)(b * SS + row) * DD + col] = f2bf(o);
        }
    }
    __syncthreads();
  }
}

extern "C" void kernel_launch(void* const* d_in, const int* in_sizes, int n_in,
                              void* d_out, int out_size, void* d_ws, size_t ws_size,
                              hipStream_t stream) {
  const float* x      = (const float*)d_in[0];
  const float* w_attn = (const float*)d_in[1];
  const float* b_attn = (const float*)d_in[2];
  const float* w_proj = (const float*)d_in[3];
  const float* b_proj = (const float*)d_in[4];
  float* out = (float*)d_out;

  char* ws = (char*)d_ws;
  short* wattnT = (short*)(ws + 8388608);             // 6291456 B
  short* wprojT = (short*)(ws + 14680064);            // 2097152 B
  short* qkv    = (short*)(ws + 16777216);            // 25165824 B (V third unused)
  short* vt     = (short*)(ws + 41943040);            // 8388608 B
  short* ctx    = (short*)(ws + 50331648);            // 8388608 B

  // prep: both weight transposes (x-cast now fused into the QKV GEMM)
  prep_k<<<4096, 256, 0, stream>>>(w_attn, wattnT, w_proj, wprojT);
  // QKV GEMM from f32 x directly: Q (scaled) + K to qkv, V transposed to vt
  gemm128_qkv_k<<<768, 256, 0, stream>>>(x, wattnT, b_attn, qkv, vt);
  flash_attn_k<<<dim3(512), 512, 0, stream>>>(qkv, vt, ctx);
  gemm128_proj_k<MTOK, DD, DD><<<256, 256, 0, stream>>>(ctx, wprojT, b_proj, out);
}

// Round 20
// 113.667 us; speedup vs baseline: 1.1558x; 1.1558x over previous
//
#include <hip/hip_runtime.h>
#include <hip/hip_bf16.h>

// GPT2 attention. B=2, S=2048, D=1024, H=16, DH=64.
// inputs (f32): x[2,2048,1024], w_attn[1024,3072], b_attn[3072], w_proj[1024,1024], b_proj[1024]
// output (f32): [2,2048,1024]

#define BB 2
#define SS 2048
#define DD 1024
#define HH 16
#define DHH 64
#define MTOK (BB * SS)        // 4096
#define N3D (3 * DD)          // 3072
// 1/sqrt(64) * log2(e): softmax runs in exp2 domain
#define QSCALE 0.18033688f

typedef __attribute__((ext_vector_type(8))) short bf16x8;
typedef __attribute__((ext_vector_type(4))) float f32x4;
typedef __attribute__((ext_vector_type(4))) short short4v;

__device__ __forceinline__ short f2bf(float f) {
  unsigned int x = __float_as_uint(f);
  unsigned int r = (x + 0x7fffu + ((x >> 16) & 1u)) >> 16;
  return (short)r;
}

__device__ __forceinline__ unsigned int cvtpk_bf16(float lo, float hi) {
  unsigned int r;
  asm("v_cvt_pk_bf16_f32 %0, %1, %2" : "=v"(r) : "v"(lo), "v"(hi));
  return r;
}

// native 2^x (v_exp_f32 IS exp2); plain exp2f() lowers to an ocml libcall.
__device__ __forceinline__ float exp2n(float x) {
  float r;
  asm("v_exp_f32 %0, %1" : "=v"(r) : "v"(x));
  return r;
}

// ---------------- fused prep: x cast + w_attn transpose + w_proj transpose ----------------
__global__ __launch_bounds__(256) void prep_k(const float* __restrict__ x, short* __restrict__ xb,
                                              const float* __restrict__ wa, short* __restrict__ waT,
                                              const float* __restrict__ wp, short* __restrict__ wpT) {
  __shared__ float t[32][33];
  int bid = blockIdx.x, tid = threadIdx.x;
  if (bid < 1024) {
    int base = bid * 1024 + tid;
#pragma unroll
    for (int j = 0; j < 4; ++j) {
      float4 v = reinterpret_cast<const float4*>(x)[base + 256 * j];
      short4v o;
      o[0] = f2bf(v.x); o[1] = f2bf(v.y); o[2] = f2bf(v.z); o[3] = f2bf(v.w);
      reinterpret_cast<short4v*>(xb)[base + 256 * j] = o;
    }
    return;
  }
  const float* W; short* Wt; int K, N, n0, k0;
  if (bid < 4096) {
    int id = bid - 1024;
    W = wa; Wt = waT; K = 1024; N = 3072;
    n0 = (id % 96) * 32; k0 = (id / 96) * 32;
  } else {
    int id = bid - 4096;
    W = wp; Wt = wpT; K = 1024; N = 1024;
    n0 = (id & 31) * 32; k0 = (id >> 5) * 32;
  }
  int tx = tid & 31, ty = tid >> 5;
#pragma unroll
  for (int i = 0; i < 4; ++i)
    t[ty + 8 * i][tx] = W[(size_t)(k0 + ty + 8 * i) * N + n0 + tx];
  __syncthreads();
#pragma unroll
  for (int i = 0; i < 4; ++i)
    Wt[(size_t)(n0 + ty + 8 * i) * K + k0 + tx] = f2bf(t[tx][ty + 8 * i]);
}

// ---------------- GEMM m97-structure, compile-time dims, XCD-chunked 1-D grid ----------------
// OUTF32=0 (QKV): bf16 out; Q cols (n0<DD) pre-scaled by QSCALE; V cols (n0>=2DD)
// written TRANSPOSED to vtout. OUTF32=1 (proj): f32 out.
template <int OUTF32, int M, int N, int K>
__global__ __launch_bounds__(256) void gemm128_k(const short* __restrict__ A,
                                                 const short* __restrict__ Bt,
                                                 const float* __restrict__ bias,
                                                 void* __restrict__ Cout,
                                                 short* __restrict__ vtout) {
  __shared__ short As[128 * 64];
  __shared__ short Bs[128 * 64];
  constexpr int NX = N / 128;
  constexpr int NWG = NX * (M / 128);
  constexpr int CHUNK = NWG / 8;  // NWG % 8 == 0 for both instantiations
  int tid = threadIdx.x;
  int swz = (blockIdx.x & 7) * CHUNK + (blockIdx.x >> 3);
  int m0 = (swz / NX) * 128, n0 = (swz % NX) * 128;
  int w = tid >> 6, lane = tid & 63;
  int wr = w >> 1, wc = w & 1;
  int ln16 = lane & 15, l16 = lane >> 4;

  f32x4 acc[4][4] = {};

  int lrow0 = w * 32 + (lane >> 3);
  int blk_p = lane & 7;

#pragma unroll 1
  for (int k0 = 0; k0 < K; k0 += 64) {
#pragma unroll
    for (int i = 0; i < 4; ++i) {
      int row_p = lrow0 + i * 8;
      int colE = ((blk_p ^ (row_p & 7)) << 3);
      __builtin_amdgcn_global_load_lds(
          (const __attribute__((address_space(1))) unsigned int*)&A[(size_t)(m0 + row_p) * K + k0 + colE],
          (__attribute__((address_space(3))) unsigned int*)&As[(w * 4 + i) * 512],
          16, 0, 0);
      __builtin_amdgcn_global_load_lds(
          (const __attribute__((address_space(1))) unsigned int*)&Bt[(size_t)(n0 + row_p) * K + k0 + colE],
          (__attribute__((address_space(3))) unsigned int*)&Bs[(w * 4 + i) * 512],
          16, 0, 0);
    }
    __syncthreads();
#pragma unroll
    for (int kk = 0; kk < 2; ++kk) {
      bf16x8 a[4], bfr[4];
#pragma unroll
      for (int mi = 0; mi < 4; ++mi) {
        int row = wr * 64 + mi * 16 + ln16;
        int blk = (kk * 4 + l16) ^ (row & 7);
        a[mi] = *reinterpret_cast<const bf16x8*>(&As[row * 64 + blk * 8]);
      }
#pragma unroll
      for (int ni = 0; ni < 4; ++ni) {
        int row = wc * 64 + ni * 16 + ln16;
        int blk = (kk * 4 + l16) ^ (row & 7);
        bfr[ni] = *reinterpret_cast<const bf16x8*>(&Bs[row * 64 + blk * 8]);
      }
#pragma unroll
      for (int mi = 0; mi < 4; ++mi)
#pragma unroll
        for (int ni = 0; ni < 4; ++ni)
          acc[mi][ni] = __builtin_amdgcn_mfma_f32_16x16x32_bf16(a[mi], bfr[ni], acc[mi][ni], 0, 0, 0);
    }
    __syncthreads();
  }

#pragma unroll
  for (int mi = 0; mi < 4; ++mi)
#pragma unroll
    for (int ni = 0; ni < 4; ++ni)
#pragma unroll
      for (int ri = 0; ri < 4; ++ri) {
        int row = m0 + wr * 64 + mi * 16 + l16 * 4 + ri;
        int col = n0 + wc * 64 + ni * 16 + ln16;
        float v = acc[mi][ni][ri] + bias[col];
        if (OUTF32) {
          reinterpret_cast<float*>(Cout)[(size_t)row * N + col] = v;
        } else {
          if (n0 < DD) v *= QSCALE;  // Q block (uniform per block)
          short bv = f2bf(v);
          if (n0 >= 2 * DD) {
            // V block: write transposed to vt
            int bb = row >> 11, s = row & 2047;
            vtout[(size_t)(bb * 1024 + col - 2 * DD) * SS + s] = bv;
          } else {
            reinterpret_cast<short*>(Cout)[(size_t)row * N + col] = bv;
          }
        }
      }
}

// ---------------- Flash attention (R17 form: l-via-ones-MFMA, setprio, XCD swizzle) ----------------
#define MASKV -3.0e38f
__global__ __launch_bounds__(512) void flash_attn_k(const short* __restrict__ qkv,
                                                    const short* __restrict__ vt,
                                                    short* __restrict__ ctx) {
  __shared__ __align__(16) char smem[53248];
  // [0,18432): Ks[2][64][72] ; [18432,36864): Vs[2][64][72] ; [36864,53248): Ps 8*16*64 shorts
  // (XOR-swizzled 16B blocks). Combine aliases: Od f32 dump at [0,16640), mls at [17408,17920),
  // lls (l dump, cacc-row layout) at [17920,18432).
  short (*Ks)[64][72] = reinterpret_cast<short(*)[64][72]>(smem);
  short (*Vs)[64][72] = reinterpret_cast<short(*)[64][72]>(smem + 18432);
  short* Psr = reinterpret_cast<short*>(smem + 36864);
  float* Od = reinterpret_cast<float*>(smem);
  float* mls = reinterpret_cast<float*>(smem + 17408);
  float* lls = reinterpret_cast<float*>(smem + 17920);

  int tid = threadIdx.x;
  // XCD-chunked swizzle: same-head blocks share an XCD L2.
  int orig = blockIdx.x;                    // 0..511
  int wg = (orig & 7) * 64 + (orig >> 3);   // bijective (512 % 8 == 0)
  int bh = wg >> 4;
  int pj = wg & 15;
  int b = bh >> 4, h = bh & 15;
  int wgv = tid >> 6, lane = tid & 63;
  int g = wgv >> 2, wq = wgv & 3;
  int ln16 = lane & 15, l16 = lane >> 4;
  int t8 = tid & 255;
  int tb = tid >> 8;  // staging parity buffer this thread fills
  int r0 = t8 >> 3, cc0 = (t8 & 7) << 3;
  int psq = (wgv << 10) + (ln16 << 6);  // Ps base (shorts) for this wave+q

  // all-ones bf16x8 (1.0 = 0x3F80) for the l row-sum MFMA
  bf16x8 vone;
#pragma unroll
  for (int j = 0; j < 8; ++j) vone[j] = (short)0x3F80;

  const short* kbase = qkv + (size_t)(b * SS) * N3D + DD + h * DHH;  // + s*N3D + d
  const short* vbase = vt + (size_t)(bh * DHH) * SS;                 // + d*SS + s

#pragma unroll 1
  for (int ti = 0; ti < 2; ++ti) {
    int qt = ti ? pj : 31 - pj;
    int q0 = qt * 64;

    bf16x8 qf[2];
    {
      const short* qrow = qkv + (size_t)(b * SS + q0 + wq * 16 + ln16) * N3D + h * DHH;
      qf[0] = *reinterpret_cast<const bf16x8*>(qrow + l16 * 8);
      qf[1] = *reinterpret_cast<const bf16x8*>(qrow + 32 + l16 * 8);
    }
    float m_ = -1e30f;
    f32x4 cacc[4] = {};
    f32x4 lacc = {};

    int ns = (qt + 2) >> 1;
    uint4 kr0, kr1, vr0, vr1;
    {
      int kt_s = tb <= qt ? tb : qt;
      kr0 = *reinterpret_cast<const uint4*>(kbase + (size_t)(kt_s * 64 + r0) * N3D + cc0);
      kr1 = *reinterpret_cast<const uint4*>(kbase + (size_t)(kt_s * 64 + r0 + 32) * N3D + cc0);
      vr0 = *reinterpret_cast<const uint4*>(vbase + (size_t)r0 * SS + kt_s * 64 + cc0);
      vr1 = *reinterpret_cast<const uint4*>(vbase + (size_t)(r0 + 32) * SS + kt_s * 64 + cc0);
    }

#pragma unroll 1
    for (int s = 0; s < ns; ++s) {
      *reinterpret_cast<uint4*>(&Ks[tb][r0][cc0]) = kr0;
      *reinterpret_cast<uint4*>(&Ks[tb][r0 + 32][cc0]) = kr1;
      *reinterpret_cast<uint4*>(&Vs[tb][r0][cc0]) = vr0;
      *reinterpret_cast<uint4*>(&Vs[tb][r0 + 32][cc0]) = vr1;
      __syncthreads();

      // prefetch next super-iter (clamped; latency hides under softmax+PV)
      {
        int kt_n = 2 * (s + 1) + tb;
        if (kt_n > qt) kt_n = qt;
        kr0 = *reinterpret_cast<const uint4*>(kbase + (size_t)(kt_n * 64 + r0) * N3D + cc0);
        kr1 = *reinterpret_cast<const uint4*>(kbase + (size_t)(kt_n * 64 + r0 + 32) * N3D + cc0);
        vr0 = *reinterpret_cast<const uint4*>(vbase + (size_t)r0 * SS + kt_n * 64 + cc0);
        vr1 = *reinterpret_cast<const uint4*>(vbase + (size_t)(r0 + 32) * SS + kt_n * 64 + cc0);
      }

      int kt_c = 2 * s + g;
      if (kt_c <= qt) {
        // QK^T swapped: sacc[ni][ri] = S^T[k = ni*16+l16*4+ri][q = ln16]  (log2-scaled)
        f32x4 sacc[4] = {};
        __builtin_amdgcn_s_setprio(1);
#pragma unroll
        for (int kk = 0; kk < 2; ++kk)
#pragma unroll
          for (int ni = 0; ni < 4; ++ni) {
            bf16x8 kf = *reinterpret_cast<const bf16x8*>(&Ks[g][ni * 16 + ln16][kk * 32 + l16 * 8]);
            sacc[ni] = __builtin_amdgcn_mfma_f32_16x16x32_bf16(kf, qf[kk], sacc[ni], 0, 0, 0);
          }
        __builtin_amdgcn_s_setprio(0);

        float p[4][4];
        float mx = MASKV;
        if (kt_c == qt) {  // diagonal tile: causal mask
          int qg = q0 + wq * 16 + ln16;
#pragma unroll
          for (int ni = 0; ni < 4; ++ni)
#pragma unroll
            for (int ri = 0; ri < 4; ++ri) {
              int kg = kt_c * 64 + ni * 16 + l16 * 4 + ri;
              float v = (kg > qg) ? MASKV : sacc[ni][ri];
              p[ni][ri] = v;
              mx = fmaxf(mx, v);
            }
        } else {
#pragma unroll
          for (int ni = 0; ni < 4; ++ni)
#pragma unroll
            for (int ri = 0; ri < 4; ++ri) {
              p[ni][ri] = sacc[ni][ri];
              mx = fmaxf(mx, sacc[ni][ri]);
            }
        }
        mx = fmaxf(mx, __shfl_xor(mx, 16));
        mx = fmaxf(mx, __shfl_xor(mx, 32));

        // defer-max (T13), log2 domain: rescale only when max grew by > 11.5
        int keep = __all(mx <= m_ + 11.5f);
        float mn = m_;
        if (!keep) {
          mn = fmaxf(m_, mx);
          float sc = exp2n(m_ - mn);
          float scr[4];
#pragma unroll
          for (int ri = 0; ri < 4; ++ri) scr[ri] = __shfl(sc, l16 * 4 + ri);
#pragma unroll
          for (int di = 0; di < 4; ++di)
#pragma unroll
            for (int ri = 0; ri < 4; ++ri) cacc[di][ri] *= scr[ri];
#pragma unroll
          for (int ri = 0; ri < 4; ++ri) lacc[ri] *= scr[ri];
          m_ = mn;
        }

#pragma unroll
        for (int ni = 0; ni < 4; ++ni)
#pragma unroll
          for (int ri = 0; ri < 4; ++ri)
            p[ni][ri] = exp2n(p[ni][ri] - mn);

        // pack P -> Ps[wave][q=ln16][k], XOR-swizzled 16B blocks (blk ^= q&7)
#pragma unroll
        for (int ni = 0; ni < 4; ++ni) {
          uint2 u;
          u.x = cvtpk_bf16(p[ni][0], p[ni][1]);
          u.y = cvtpk_bf16(p[ni][2], p[ni][3]);
          int idx = psq + ((((ni << 1) + (l16 >> 1)) ^ (ln16 & 7)) << 3) + ((l16 & 1) << 2);
          *reinterpret_cast<uint2*>(&Psr[idx]) = u;
        }
        asm volatile("s_waitcnt lgkmcnt(0)" ::: "memory");

        // ctx += P @ V ; l += P @ ones (same C-layout: row = l16*4+ri)
        __builtin_amdgcn_s_setprio(1);
#pragma unroll
        for (int kk = 0; kk < 2; ++kk) {
          bf16x8 pa = *reinterpret_cast<const bf16x8*>(
              &Psr[psq + ((((kk << 2) + l16) ^ (ln16 & 7)) << 3)]);
          lacc = __builtin_amdgcn_mfma_f32_16x16x32_bf16(pa, vone, lacc, 0, 0, 0);
#pragma unroll
          for (int di = 0; di < 4; ++di) {
            bf16x8 vb = *reinterpret_cast<const bf16x8*>(&Vs[g][di * 16 + ln16][kk * 32 + l16 * 8]);
            cacc[di] = __builtin_amdgcn_mfma_f32_16x16x32_bf16(pa, vb, cacc[di], 0, 0, 0);
          }
        }
        __builtin_amdgcn_s_setprio(0);
      }
      __syncthreads();
    }

    // ---- combine even/odd partials (aliases Ks/Vs region; all kv reads done) ----
    if (g == 1) {
      if (l16 == 0) mls[wq * 16 + ln16] = m_;
      if (ln16 == 0)
#pragma unroll
        for (int ri = 0; ri < 4; ++ri) lls[wq * 16 + l16 * 4 + ri] = lacc[ri];
#pragma unroll
      for (int di = 0; di < 4; ++di)
#pragma unroll
        for (int ri = 0; ri < 4; ++ri)
          Od[wq * 1040 + (l16 * 4 + ri) * 65 + di * 16 + ln16] = cacc[di][ri];
    }
    __syncthreads();
    if (g == 0) {
      float m1 = mls[wq * 16 + ln16];
      float mM = fmaxf(m_, m1);
      float e0 = exp2n(m_ - mM), e1 = exp2n(m1 - mM);
      float e0r[4], e1r[4], ivr[4];
#pragma unroll
      for (int ri = 0; ri < 4; ++ri) {
        int src = l16 * 4 + ri;
        e0r[ri] = __shfl(e0, src);
        e1r[ri] = __shfl(e1, src);
      }
#pragma unroll
      for (int ri = 0; ri < 4; ++ri) {
        float l1 = lls[wq * 16 + l16 * 4 + ri];
        ivr[ri] = 1.f / (lacc[ri] * e0r[ri] + l1 * e1r[ri]);
      }
#pragma unroll
      for (int di = 0; di < 4; ++di)
#pragma unroll
        for (int ri = 0; ri < 4; ++ri) {
          float a1 = Od[wq * 1040 + (l16 * 4 + ri) * 65 + di * 16 + ln16];
          float o = (cacc[di][ri] * e0r[ri] + a1 * e1r[ri]) * ivr[ri];
          int row = q0 + wq * 16 + l16 * 4 + ri;
          int col = h * DHH + di * 16 + ln16;
          ctx[(size_t)(b * SS + row) * DD + col] = f2bf(o);
        }
    }
    __syncthreads();
  }
}

extern "C" void kernel_launch(void* const* d_in, const int* in_sizes, int n_in,
                              void* d_out, int out_size, void* d_ws, size_t ws_size,
                              hipStream_t stream) {
  const float* x      = (const float*)d_in[0];
  const float* w_attn = (const float*)d_in[1];
  const float* b_attn = (const float*)d_in[2];
  const float* w_proj = (const float*)d_in[3];
  const float* b_proj = (const float*)d_in[4];
  float* out = (float*)d_out;

  char* ws = (char*)d_ws;
  short* xb     = (short*)(ws);                       // 8388608 B
  short* wattnT = (short*)(ws + 8388608);             // 6291456 B
  short* wprojT = (short*)(ws + 14680064);            // 2097152 B
  short* qkv    = (short*)(ws + 16777216);            // 25165824 B (V third unused)
  short* vt     = (short*)(ws + 41943040);            // 8388608 B
  short* ctx    = (short*)(ws + 50331648);            // 8388608 B

  // fused prep: x cast + both weight transposes in one launch
  prep_k<<<5120, 256, 0, stream>>>(x, xb, w_attn, wattnT, w_proj, wprojT);
  // QKV GEMM: Q (scaled) + K to qkv, V transposed to vt. 1-D XCD-chunked grid.
  gemm128_k<0, MTOK, N3D, DD><<<(N3D / 128) * (MTOK / 128), 256, 0, stream>>>(
      xb, wattnT, b_attn, qkv, vt);
  flash_attn_k<<<dim3(512), 512, 0, stream>>>(qkv, vt, ctx);
  gemm128_k<1, MTOK, DD, DD><<<(DD / 128) * (MTOK / 128), 256, 0, stream>>>(
      ctx, wprojT, b_proj, out, nullptr);
}